// Round 13
// baseline (1817.690 us; speedup 1.0000x reference)
//
#include <hip/hip_runtime.h>
#include <math.h>

// FCOS RPN head, R13: conv body reverted to R11 (R12 prefetch regressed);
// oc-split pushed to by=4/NT=1 (2760 blocks, LDS-capped 6 blocks/CU ~ 24
// waves/CU vs 27% occupancy at R11's 1380 blocks). Indexing generalized,
// bijective, accumulation order bit-identical. NMS bitmatrix chain unchanged.

#define KCLS 80
#define TOPKK 1000
#define NCAND 5000
#define MAXDET 100
#define TOTHW 20267
#define TT 345

constexpr int cHa[5]  = {100, 50, 25, 13, 7};
constexpr int cWa[5]  = {152, 76, 38, 19, 10};
constexpr int cHWa[5] = {15200, 3800, 950, 247, 70};
constexpr int cPa[5]  = {0, 15200, 19000, 19950, 20197};
constexpr int cTXa[5] = {19, 10, 5, 3, 2};
constexpr int cPTa[5] = {0, 247, 317, 337, 343};
constexpr int cTa[5]  = {247, 70, 20, 6, 2};
constexpr float cSa[5] = {8.f, 16.f, 32.f, 64.f, 128.f};
constexpr int cPCh[5] = {0, 238, 298, 313, 317};

typedef _Float16 h8 __attribute__((ext_vector_type(8)));
typedef float f4 __attribute__((ext_vector_type(4)));

struct FeatPtrs { const float* p[5]; };

__device__ __forceinline__ int lvl_of_tile(int bx) {
  return (bx < 247) ? 0 : (bx < 317) ? 1 : (bx < 337) ? 2 : (bx < 343) ? 3 : 4;
}
__device__ __forceinline__ int lvl_of_pix(int gi) {
  return (gi < 15200) ? 0 : (gi < 19000) ? 1 : (gi < 19950) ? 2 : (gi < 20197) ? 3 : 4;
}

// ---------------- feats transpose: [c][H][W] -> FT[n][gi][256] --------------
__global__ __launch_bounds__(256) void k_tf(FeatPtrs fp, float* __restrict__ FT) {
  int b = blockIdx.x, n = blockIdx.y;
  int l = (b < 238) ? 0 : (b < 298) ? 1 : (b < 313) ? 2 : (b < 317) ? 3 : 4;
  int ch = b - cPCh[l];
  int HW = cHWa[l];
  int px0 = ch * 64;
  const float* src = fp.p[l] + (size_t)n * 256 * HW;
  __shared__ float tile[64][65];
  int tid = threadIdx.x;
  int a0 = tid & 63, a1 = tid >> 6;
  for (int icc = 0; icc < 256; icc += 64) {
    __syncthreads();
#pragma unroll
    for (int j = 0; j < 16; ++j) {
      int ic = icc + a1 * 16 + j;
      int px = px0 + a0;
      tile[a0][a1 * 16 + j] = (px < HW) ? src[(size_t)ic * HW + px] : 0.f;
    }
    __syncthreads();
#pragma unroll
    for (int j = 0; j < 16; ++j) {
      int pxl = a1 * 16 + j;
      int px = px0 + pxl;
      if (px < HW)
        FT[((size_t)(n * TOTHW + cPa[l] + px)) * 256 + icc + a0] = tile[pxl][a0];
    }
  }
}

// ---------------- weight repack to MFMA B-fragment order, f16 split ----------
__global__ void k_rep(const float* __restrict__ w, const float* __restrict__ w2,
                      _Float16* __restrict__ Wh, _Float16* __restrict__ Wl,
                      int OC, int OCpad) {
  int i = blockIdx.x * 256 + threadIdx.x;
  int tot = 2304 * OCpad;
  if (i >= tot) return;
  int j = i & 7, kh = (i >> 3) & 3, c = (i >> 5) & 15;
  int rest = i >> 9;
  int G = OCpad >> 4;
  int g = rest % G, ti = rest / G;
  int ics = ti & 7, t = ti >> 3;
  int oc = g * 16 + c, ic = ics * 32 + kh * 8 + j;
  float v = 0.f;
  if (oc < OC) v = w[((size_t)oc * 256 + ic) * 9 + t];
  else if (w2 != nullptr && oc == OC) v = w2[(size_t)ic * 9 + t];
  float sv = v * 2048.f;
  _Float16 h = (_Float16)sv;
  Wh[i] = h;
  Wl[i] = (_Float16)(sv - (float)h);
}

// ---------------- MFMA conv3x3 pad=1 Cin=256, all levels batched -------------
// block 256thr = 4 waves; 8x8 tile; wave -> 64px x NT*16 oc; blockIdx.y splits
// the OC dimension (by*64*NT oc base) for occupancy.
template<bool AFFINE, bool GN_PART, bool HEAD, int NT>
__global__ __launch_bounds__(256) void k_cmf(
    const float* __restrict__ actIn,
    const _Float16* __restrict__ Wh, const _Float16* __restrict__ Wl,
    const float* __restrict__ bias1, const float* __restrict__ bias2,
    const float* __restrict__ cab, float* __restrict__ out,
    int outCH, int OC, int OCpad, double* __restrict__ part) {
  const int bx = blockIdx.x;
  const int by = blockIdx.y;
  const int lvl = lvl_of_tile(bx);
  const int tile = bx - cPTa[lvl];
  const int H = cHa[lvl], W = cWa[lvl];
  const int tx0 = (tile % cTXa[lvl]) * 8, ty0 = (tile / cTXa[lvl]) * 8;
  const int n = blockIdx.z;
  const int t = threadIdx.x, wv = t >> 6, lane = t & 63;
  const int kh = lane >> 4, c = lane & 15;
  const int Gt = OCpad >> 4;
  const int gbase = by * (4 * NT) + wv * NT;
  const int wsel = by * (64 * NT) + wv * (16 * NT);

  __shared__ _Float16 sH[6400];
  __shared__ _Float16 sL[6400];

  const float* cabL = cab + (size_t)(lvl * 2 + n) * 512;

  const float* sp[4];
  int shp[4], sgp[4];
  bool sinb[4], shas[4];
#pragma unroll
  for (int s = 0; s < 4; ++s) {
    int e = t + 256 * s;
    bool has = e < 800;
    int grp = e & 7, hp = e >> 3;
    if (hp > 99) hp = 99;
    int yy = hp / 10, xx = hp % 10;
    int gy = ty0 + yy - 1, gx = tx0 + xx - 1;
    bool inb = has && ((unsigned)gy < (unsigned)H) && ((unsigned)gx < (unsigned)W);
    int gpx = inb ? (cPa[lvl] + gy * W + gx) : 0;
    sp[s] = actIn + ((size_t)(n * TOTHW + gpx)) * 256 + grp * 8;
    shp[s] = hp; sgp[s] = grp; sinb[s] = inb; shas[s] = has;
  }

  f4 acc[4][NT];
#pragma unroll
  for (int m = 0; m < 4; ++m)
#pragma unroll
    for (int nt = 0; nt < NT; ++nt) acc[m][nt] = (f4)(0.f);

  float4 fv[4][2];
#pragma unroll
  for (int s = 0; s < 4; ++s) {
    if (sinb[s]) {
      fv[s][0] = *(const float4*)(sp[s]);
      fv[s][1] = *(const float4*)(sp[s] + 4);
    } else {
      fv[s][0] = make_float4(0.f, 0.f, 0.f, 0.f);
      fv[s][1] = make_float4(0.f, 0.f, 0.f, 0.f);
    }
  }

  const int lB = (c * 4 + kh) * 8;

#pragma unroll 1
  for (int icc = 0; icc < 256; icc += 64) {
    __syncthreads();
#pragma unroll
    for (int s = 0; s < 4; ++s) {
      if (shas[s]) {
        float vv[8];
        vv[0] = fv[s][0].x; vv[1] = fv[s][0].y; vv[2] = fv[s][0].z; vv[3] = fv[s][0].w;
        vv[4] = fv[s][1].x; vv[5] = fv[s][1].y; vv[6] = fv[s][1].z; vv[7] = fv[s][1].w;
        if (AFFINE && sinb[s]) {
#pragma unroll
          for (int j = 0; j < 8; ++j) {
            int ch = icc + sgp[s] * 8 + j;
            vv[j] = fmaxf(0.f, fmaf(vv[j], cabL[2 * ch], cabL[2 * ch + 1]));
          }
        }
        h8 hv, lv2;
#pragma unroll
        for (int j = 0; j < 8; ++j) {
          float sv = vv[j] * 32.f;
          _Float16 hh = (_Float16)sv;
          hv[j] = hh;
          lv2[j] = (_Float16)(sv - (float)hh);
        }
        int boff = ((shp[s] << 7) + (sgp[s] << 4)) ^ ((shp[s] & 7) << 4);
        *(h8*)((char*)sH + boff) = hv;
        *(h8*)((char*)sL + boff) = lv2;
      }
    }
    if (icc < 192) {
#pragma unroll
      for (int s = 0; s < 4; ++s) {
        if (sinb[s]) {
          fv[s][0] = *(const float4*)(sp[s] + icc + 64);
          fv[s][1] = *(const float4*)(sp[s] + icc + 68);
        }
      }
    }
    __syncthreads();

#pragma unroll 1
    for (int dy = 0; dy < 3; ++dy) {
#pragma unroll 1
      for (int dx = 0; dx < 3; ++dx) {
        const int t9 = dy * 3 + dx;
#pragma unroll
        for (int ics = 0; ics < 2; ++ics) {
          const int ICS = (icc >> 5) + ics;
          size_t wb = ((size_t)(t9 * 8 + ICS) * Gt + gbase) * 512 + lB;
          h8 bh[NT], bl[NT];
#pragma unroll
          for (int nt = 0; nt < NT; ++nt) {
            bh[nt] = *(const h8*)(Wh + wb + nt * 512);
            bl[nt] = *(const h8*)(Wl + wb + nt * 512);
          }
#pragma unroll
          for (int m = 0; m < 4; ++m) {
            int pxA = m * 16 + c;
            int hpA = ((pxA >> 3) + dy) * 10 + (pxA & 7) + dx;
            int boffA = ((hpA << 7) + (ics << 6) + (kh << 4)) ^ ((hpA & 7) << 4);
            h8 Ah = *(const h8*)((const char*)sH + boffA);
            h8 Al = *(const h8*)((const char*)sL + boffA);
#pragma unroll
            for (int nt = 0; nt < NT; ++nt) {
              acc[m][nt] = __builtin_amdgcn_mfma_f32_16x16x32_f16(Ah, bh[nt], acc[m][nt], 0, 0, 0);
              acc[m][nt] = __builtin_amdgcn_mfma_f32_16x16x32_f16(Ah, bl[nt], acc[m][nt], 0, 0, 0);
              acc[m][nt] = __builtin_amdgcn_mfma_f32_16x16x32_f16(Al, bh[nt], acc[m][nt], 0, 0, 0);
            }
          }
        }
      }
    }
  }

  const float inv = 1.f / 65536.f;
#pragma unroll
  for (int nt = 0; nt < NT; ++nt) {
    int oc = wsel + nt * 16 + c;
    float bb;
    if (HEAD) bb = (oc < KCLS) ? bias1[oc] : (oc == KCLS ? bias2[0] : 0.f);
    else bb = (oc < OC) ? bias1[oc] : 0.f;
    double s = 0.0, ss = 0.0;
#pragma unroll
    for (int m = 0; m < 4; ++m) {
#pragma unroll
      for (int r = 0; r < 4; ++r) {
        int px = m * 16 + kh * 4 + r;
        int oy = ty0 + (px >> 3), ox = tx0 + (px & 7);
        bool vpx = (oy < H) && (ox < W);
        float y = fmaf(acc[m][nt][r], inv, bb);
        if (vpx && oc < OC)
          out[((size_t)(n * TOTHW + cPa[lvl] + oy * W + ox)) * outCH + oc] = y;
        if (GN_PART && vpx) { double d = (double)y; s += d; ss += d * d; }
      }
    }
    if (GN_PART) {
#pragma unroll
      for (int msk = 16; msk <= 32; msk <<= 1) {
        s += __shfl_xor(s, msk, 64);
        ss += __shfl_xor(ss, msk, 64);
      }
#pragma unroll
      for (int msk = 1; msk <= 4; msk <<= 1) {
        s += __shfl_xor(s, msk, 64);
        ss += __shfl_xor(ss, msk, 64);
      }
      if (lane == 0 || lane == 8) {
        int G = by * (8 * NT) + wv * (2 * NT) + nt * 2 + (lane >> 3);
        size_t sl = (((size_t)bx * 2 + n) * 32 + G) * 2;
        part[sl] = s;
        part[sl + 1] = ss;
      }
    }
  }
}

// ---------------- GN coef from per-tile partials -----------------------------
__global__ __launch_bounds__(256) void k_coef(const double* __restrict__ part,
                                              const float* __restrict__ gs,
                                              const float* __restrict__ gb,
                                              float* __restrict__ cab) {
  int l = blockIdx.x >> 6, ng = blockIdx.x & 63, n = ng >> 5, g = ng & 31;
  int T = cTa[l];
  double s = 0.0, ss = 0.0;
  for (int tt = threadIdx.x; tt < T; tt += 256) {
    size_t sl = (((size_t)(cPTa[l] + tt) * 2 + n) * 32 + g) * 2;
    s += part[sl]; ss += part[sl + 1];
  }
  __shared__ double rs[256], rss[256];
  rs[threadIdx.x] = s; rss[threadIdx.x] = ss;
  __syncthreads();
  for (int off = 128; off > 0; off >>= 1) {
    if (threadIdx.x < off) {
      rs[threadIdx.x] += rs[threadIdx.x + off];
      rss[threadIdx.x] += rss[threadIdx.x + off];
    }
    __syncthreads();
  }
  if (threadIdx.x == 0) {
    int len = 8 * cHWa[l];
    double mu = rs[0] / len;
    double var = rss[0] / len - mu * mu;
    double rsq = 1.0 / sqrt(var + 1e-5);
    for (int cc = 0; cc < 8; ++cc) {
      int ch = g * 8 + cc;
      double A = rsq * (double)gs[ch];
      cab[((size_t)(l * 2 + n) * 256 + ch) * 2] = (float)A;
      cab[((size_t)(l * 2 + n) * 256 + ch) * 2 + 1] = (float)((double)gb[ch] - mu * A);
    }
  }
}

// ---------------- decode scores ---------------------------------------------
__global__ void k_dscore(const float* __restrict__ LG, float* __restrict__ SF) {
  size_t i = (size_t)blockIdx.x * 256 + threadIdx.x;
  size_t tot = (size_t)2 * TOTHW * 80;
  if (i >= tot) return;
  int c = (int)(i % 80);
  size_t g = i / 80;
  const float* base = LG + g * 96;
  float lg = base[c];
  float ct = base[80];
  float s1 = 1.f / (1.f + expf(-lg));
  float s2 = 1.f / (1.f + expf(-ct));
  SF[i] = sqrtf(s1 * s2);
}

// ---------------- decode boxes ----------------------------------------------
__global__ void k_dbox(const float* __restrict__ RG, const float* __restrict__ scales,
                       float* __restrict__ BX) {
  int i = blockIdx.x * 256 + threadIdx.x;
  if (i >= 2 * TOTHW) return;
  int gi = i % TOTHW;
  int l = lvl_of_pix(gi);
  int a = gi - cPa[l];
  int W = cWa[l];
  const float* rg = RG + (size_t)i * 8;
  float sc = scales[l];
  float stride = cSa[l];
  float r0 = fmaxf(0.f, sc * rg[0]);
  float r1 = fmaxf(0.f, sc * rg[1]);
  float r2 = fmaxf(0.f, sc * rg[2]);
  float r3 = fmaxf(0.f, sc * rg[3]);
  int x = a % W, yv = a / W;
  float px = (x + 0.5f) * stride, py = (yv + 0.5f) * stride;
  float* bp = BX + (size_t)i * 4;
  bp[0] = px - r0 * stride; bp[1] = py - r1 * stride;
  bp[2] = px + r2 * stride; bp[3] = py + r3 * stride;
}

// ---------------- exact top-1000 per (n,level) -------------------------------
__global__ void k_hist1(const float* __restrict__ SF, unsigned* __restrict__ hist) {
  int nl = blockIdx.y; int n = nl & 1, l = nl >> 1;
  const float* s = SF + ((size_t)n * TOTHW + cPa[l]) * 80;
  int M = cHWa[l] * 80;
  unsigned* h = hist + nl * 1024;
  __shared__ unsigned lh[1024];
  for (int i = threadIdx.x; i < 1024; i += blockDim.x) lh[i] = 0;
  __syncthreads();
  for (int i = blockIdx.x * blockDim.x + threadIdx.x; i < M; i += gridDim.x * blockDim.x) {
    unsigned key = __float_as_uint(s[i]);
    unsigned b = key >> 20; if (b > 1023u) b = 1023u;
    atomicAdd(&lh[b], 1u);
  }
  __syncthreads();
  for (int i = threadIdx.x; i < 1024; i += blockDim.x)
    if (lh[i]) atomicAdd(&h[i], lh[i]);
}

__global__ __launch_bounds__(256) void k_resolve1(const unsigned* __restrict__ hist,
                                                  unsigned* __restrict__ ctl) {
  int nl = blockIdx.x;
  const unsigned* h = hist + nl * 1024;
  int t = threadIdx.x;
  unsigned loc[4];
  unsigned chunk = 0;
#pragma unroll
  for (int j = 0; j < 4; ++j) { loc[j] = h[t * 4 + j]; chunk += loc[j]; }
  __shared__ unsigned csum[256];
  csum[t] = chunk;
  __syncthreads();
  for (int off = 1; off < 256; off <<= 1) {
    unsigned v = (t + off < 256) ? csum[t + off] : 0u;
    __syncthreads();
    csum[t] += v;
    __syncthreads();
  }
  unsigned above = csum[t] - chunk;
  unsigned sfx[5];
  sfx[4] = above;
#pragma unroll
  for (int j = 3; j >= 0; --j) sfx[j] = sfx[j + 1] + loc[j];
#pragma unroll
  for (int j = 0; j < 4; ++j) {
    if (sfx[j] >= TOPKK && sfx[j + 1] < TOPKK) {
      ctl[nl] = (unsigned)(t * 4 + j);
      ctl[10 + nl] = sfx[j + 1];
    }
  }
}

__global__ void k_hist2(const float* __restrict__ SF, const unsigned* __restrict__ ctl,
                        unsigned* __restrict__ hist2) {
  int nl = blockIdx.y; int n = nl & 1, l = nl >> 1;
  unsigned b1 = ctl[nl];
  const float* s = SF + ((size_t)n * TOTHW + cPa[l]) * 80;
  int M = cHWa[l] * 80;
  unsigned* h = hist2 + nl * 4096;
  __shared__ unsigned lh[4096];
  for (int i = threadIdx.x; i < 4096; i += blockDim.x) lh[i] = 0;
  __syncthreads();
  for (int i = blockIdx.x * blockDim.x + threadIdx.x; i < M; i += gridDim.x * blockDim.x) {
    unsigned key = __float_as_uint(s[i]);
    if ((key >> 20) == b1) atomicAdd(&lh[(key >> 8) & 0xFFFu], 1u);
  }
  __syncthreads();
  for (int i = threadIdx.x; i < 4096; i += blockDim.x)
    if (lh[i]) atomicAdd(&h[i], lh[i]);
}

__global__ __launch_bounds__(256) void k_resolve2(const unsigned* __restrict__ hist2,
                                                  const unsigned* __restrict__ ctlin,
                                                  unsigned* __restrict__ ctl) {
  int nl = blockIdx.x;
  const unsigned* h = hist2 + nl * 4096;
  unsigned b1 = ctlin[nl];
  unsigned m1 = ctlin[10 + nl];
  int t = threadIdx.x;
  unsigned loc[16];
  unsigned chunk = 0;
#pragma unroll
  for (int j = 0; j < 16; ++j) { loc[j] = h[t * 16 + j]; chunk += loc[j]; }
  __shared__ unsigned csum[256];
  csum[t] = chunk;
  __syncthreads();
  for (int off = 1; off < 256; off <<= 1) {
    unsigned v = (t + off < 256) ? csum[t + off] : 0u;
    __syncthreads();
    csum[t] += v;
    __syncthreads();
  }
  unsigned above = csum[t] - chunk;
  unsigned sfx[17];
  sfx[16] = above;
#pragma unroll
  for (int j = 15; j >= 0; --j) sfx[j] = sfx[j + 1] + loc[j];
#pragma unroll
  for (int j = 0; j < 16; ++j) {
    if (m1 + sfx[j] >= TOPKK && m1 + sfx[j + 1] < TOPKK)
      ctl[20 + nl] = (b1 << 12) | (unsigned)(t * 16 + j);
  }
}

__device__ __forceinline__ void write_cand(int n, int l, int pos, float v, int i,
                                           float* csc, float* ccl, int* gai) {
  int a = i / KCLS, c = i - a * KCLS;
  int g = n * NCAND + pos;
  csc[g] = (v > 0.05f) ? v : 0.f;
  ccl[g] = (float)c;
  gai[g] = cPa[l] + a;
}

__global__ void k_compact(const float* __restrict__ SF, const unsigned* __restrict__ ctl,
                          unsigned* __restrict__ cnt, float* __restrict__ eqV,
                          unsigned* __restrict__ eqI,
                          float* csc, float* ccl, int* gai) {
  int nl = blockIdx.y; int n = nl & 1, l = nl >> 1;
  const float* s = SF + ((size_t)n * TOTHW + cPa[l]) * 80;
  int M = cHWa[l] * 80;
  unsigned P = ctl[20 + nl];
  int loff = l * TOPKK;
  for (int i = blockIdx.x * blockDim.x + threadIdx.x; i < M; i += gridDim.x * blockDim.x) {
    float v = s[i];
    unsigned k24 = __float_as_uint(v) >> 8;
    if (k24 < P) continue;
    if (k24 > P) {
      unsigned slot = atomicAdd(&cnt[nl], 1u);
      write_cand(n, l, loff + (int)slot, v, i, csc, ccl, gai);
    } else {
      unsigned e = atomicAdd(&cnt[10 + nl], 1u);
      if (e < 2048u) { eqV[nl * 2048 + e] = v; eqI[nl * 2048 + e] = (unsigned)i; }
    }
  }
}

__global__ void k_eq(const float* __restrict__ eqV, const unsigned* __restrict__ eqI,
                     const unsigned* __restrict__ cnt,
                     float* csc, float* ccl, int* gai) {
  int nl = blockIdx.x; int n = nl & 1, l = nl >> 1;
  int above = (int)cnt[nl];
  unsigned ec = cnt[10 + nl];
  int E = ec < 2048u ? (int)ec : 2048;
  int r = TOPKK - above;
  int loff = l * TOPKK;
  for (int e = threadIdx.x; e < E; e += blockDim.x) {
    float v = eqV[nl * 2048 + e];
    unsigned idx = eqI[nl * 2048 + e];
    int rank = 0;
    for (int j = 0; j < E; ++j) {
      float vj = eqV[nl * 2048 + j];
      unsigned ij = eqI[nl * 2048 + j];
      if (vj > v || (vj == v && ij < idx)) rank++;
    }
    if (rank < r)
      write_cand(n, l, loff + above + rank, v, (int)idx, csc, ccl, gai);
  }
}

// ---------------- gather candidate boxes -------------------------------------
__global__ void k_gather(const int* __restrict__ gai, const float* __restrict__ ccl,
                         const float* __restrict__ BX,
                         float* __restrict__ cbx, float* __restrict__ cob) {
  int i = blockIdx.x * 256 + threadIdx.x;
  if (i >= 2 * NCAND) return;
  int n = i / NCAND;
  int a = gai[i];
  if (a < 0 || a >= TOTHW) a = 0;
  const float* bp = BX + ((size_t)n * TOTHW + a) * 4;
  float b0 = bp[0], b1 = bp[1], b2 = bp[2], b3 = bp[3];
  float off = ccl[i] * 1e4f;
  cbx[(size_t)i * 4 + 0] = b0; cbx[(size_t)i * 4 + 1] = b1;
  cbx[(size_t)i * 4 + 2] = b2; cbx[(size_t)i * 4 + 3] = b3;
  cob[(size_t)i * 4 + 0] = b0 + off; cob[(size_t)i * 4 + 1] = b1 + off;
  cob[(size_t)i * 4 + 2] = b2 + off; cob[(size_t)i * 4 + 3] = b3 + off;
}

// ---------------- NMS stage 1: exact rank by (score desc, idx asc) ----------
__global__ __launch_bounds__(256) void k_rank(
    const float* __restrict__ csc, const float* __restrict__ cob,
    float* __restrict__ SSC, float* __restrict__ SAR,
    int* __restrict__ SIDX, float4* __restrict__ SOX) {
  int n = blockIdx.x / 20, seg = blockIdx.x % 20;
  int i = seg * 256 + threadIdx.x;
  bool act = i < NCAND;
  float sci = act ? csc[(size_t)n * NCAND + i] : 0.f;
  int rank = 0;
  __shared__ float tj[256];
  for (int jt = 0; jt < 20; ++jt) {
    int j = jt * 256 + threadIdx.x;
    tj[threadIdx.x] = (j < NCAND) ? csc[(size_t)n * NCAND + j] : -2.f;
    __syncthreads();
    if (act) {
      for (int k = 0; k < 256; ++k) {
        int jj = jt * 256 + k;
        float v = tj[k];
        rank += (v > sci || (v == sci && jj < i)) ? 1 : 0;
      }
    }
    __syncthreads();
  }
  if (act) {
    float4 b = *(const float4*)(cob + ((size_t)n * NCAND + i) * 4);
    size_t r = (size_t)n * NCAND + rank;
    SSC[r] = sci;
    SAR[r] = fmaxf(b.z - b.x, 0.f) * fmaxf(b.w - b.y, 0.f);
    SIDX[r] = i;
    SOX[r] = b;
  }
}

// ---------------- NMS stage 2: suppression bit-matrix (sorted order) ---------
__global__ __launch_bounds__(256) void k_bmat(
    const float4* __restrict__ SOX, const float* __restrict__ SAR,
    unsigned long long* __restrict__ mat) {
  int n = blockIdx.y;
  int i = blockIdx.x * 4 + (threadIdx.x >> 6);
  int lane = threadIdx.x & 63;
  size_t base = (size_t)n * NCAND;
  float4 bi = SOX[base + i];
  float ai = SAR[base + i];
  unsigned long long* row = mat + ((size_t)n * NCAND + i) * 80;
  for (int c = i >> 6; c < 79; ++c) {
    int j = c * 64 + lane;
    bool bit = false;
    if (j < NCAND) {
      float4 bj = SOX[base + j];
      float iw = fmaxf(fminf(bi.z, bj.z) - fmaxf(bi.x, bj.x), 0.f);
      float ih = fmaxf(fminf(bi.w, bj.w) - fmaxf(bi.y, bj.y), 0.f);
      float inter = iw * ih;
      float iou = inter / fmaxf(ai + SAR[base + j] - inter, 1e-6f);
      bit = (iou > 0.6f) || (j == i);
    }
    unsigned long long m = __ballot(bit);
    if (lane == 0) row[c] = m;
  }
}

// ---------------- NMS stage 3: 1-wave greedy walk ----------------------------
__global__ __launch_bounds__(64) void k_walk(
    const float* __restrict__ SSC, const int* __restrict__ SIDX,
    const unsigned long long* __restrict__ mat,
    const float* __restrict__ cbox, const float* __restrict__ ccls,
    float* __restrict__ out) {
  int n = blockIdx.x;
  int l = threadIdx.x;
  __shared__ float sS[NCAND];
  __shared__ int pk[MAXDET];
  __shared__ float pv[MAXDET];
  for (int j = l; j < NCAND; j += 64) sS[j] = SSC[(size_t)n * NCAND + j];
  unsigned long long a0 = ~0ull;
  unsigned long long a1 = (l < 14) ? ~0ull : (l == 14 ? 0xFFull : 0ull);
  __syncthreads();
  for (int it = 0; it < MAXDET; ++it) {
    int j0 = a0 ? (l * 64 + __ffsll((long long)a0) - 1) : (1 << 30);
    int j1 = a1 ? ((64 + l) * 64 + __ffsll((long long)a1) - 1) : (1 << 30);
    int loc = j0 < j1 ? j0 : j1;
#pragma unroll
    for (int off = 1; off < 64; off <<= 1) {
      int o = __shfl_xor(loc, off);
      loc = o < loc ? o : loc;
    }
    float bv = (loc < NCAND) ? sS[loc] : 0.f;
    if (bv > 0.f) {
      const unsigned long long* row = mat + ((size_t)n * NCAND + loc) * 80;
      a0 &= ~row[l];
      if (l < 15) a1 &= ~row[64 + l];
      if (l == 0) { pk[it] = loc; pv[it] = bv; }
    } else {
      if (l == 0) { pk[it] = -1; pv[it] = 0.f; }
    }
  }
  __syncthreads();
  for (int it = l; it < MAXDET; it += 64) {
    float* o = out + ((size_t)n * MAXDET + it) * 6;
    int p = pk[it];
    if (p >= 0) {
      int orig = SIDX[(size_t)n * NCAND + p];
      size_t g = (size_t)n * NCAND + orig;
      const float* bb = cbox + g * 4;
      o[0] = bb[0]; o[1] = bb[1]; o[2] = bb[2]; o[3] = bb[3];
      o[4] = pv[it]; o[5] = ccls[g];
    } else {
      o[0] = o[1] = o[2] = o[3] = o[4] = o[5] = 0.f;
    }
  }
}

// ---------------- host orchestration -----------------------------------------
extern "C" void kernel_launch(void* const* d_in, const int* in_sizes, int n_in,
                              void* d_out, int out_size, void* d_ws, size_t ws_size,
                              hipStream_t stream) {
  FeatPtrs fp;
  for (int i = 0; i < 5; ++i) fp.p[i] = (const float*)d_in[i];
  const float* cls_w = (const float*)d_in[5];
  const float* cls_b = (const float*)d_in[6];
  const float* cls_gs = (const float*)d_in[7];
  const float* cls_gb = (const float*)d_in[8];
  const float* box_w = (const float*)d_in[9];
  const float* box_b = (const float*)d_in[10];
  const float* box_gs = (const float*)d_in[11];
  const float* box_gb = (const float*)d_in[12];
  const float* score_w = (const float*)d_in[13];
  const float* score_b = (const float*)d_in[14];
  const float* bbox_w = (const float*)d_in[15];
  const float* bbox_b = (const float*)d_in[16];
  const float* ctr_w = (const float*)d_in[17];
  const float* ctr_b = (const float*)d_in[18];
  const float* scales = (const float*)d_in[19];

  float* ws = (float*)d_ws;
  const size_t A_off    = 0;
  const size_t B_off    = 10376704;
  const size_t WTh_off  = 20753408;
  const size_t WTl_off  = 21933056;
  const size_t WSh_off  = 23112704;
  const size_t WSl_off  = 23260160;
  const size_t WBh_off  = 23407616;
  const size_t WBl_off  = 23481344;
  const size_t PART_off = 23555072;
  const size_t CAB_off  = 23731712;
  const size_t CSC_off  = 23736832;
  const size_t CCL_off  = 23746832;
  const size_t GAI_off  = 23756832;
  const size_t H1_off   = 23766832;
  const size_t H2_off   = 23777072;
  const size_t CNT_off  = 23818032;
  const size_t CTL_off  = 23818064;
  const size_t EQV_off  = 23818096;
  const size_t EQI_off  = 23838576;
  const size_t LG_off   = A_off + 0;
  const size_t SF_off   = A_off + 4000000;
  const size_t RG_off   = A_off + 7300000;
  const size_t BX_off   = A_off + 7700000;
  const size_t CBX_off  = A_off + 7900000;
  const size_t COB_off  = A_off + 7950000;
  const size_t SSCs_off = A_off + 8000000;
  const size_t SARs_off = A_off + 8010000;
  const size_t SIDX_off = A_off + 8020000;
  const size_t SOXs_off = A_off + 8030000;
  const size_t MAT_off  = A_off + 8100000;

  float* A = ws + A_off;
  float* B = ws + B_off;
  _Float16* WTh = (_Float16*)(ws + WTh_off);
  _Float16* WTl = (_Float16*)(ws + WTl_off);
  _Float16* WSh = (_Float16*)(ws + WSh_off);
  _Float16* WSl = (_Float16*)(ws + WSl_off);
  _Float16* WBh = (_Float16*)(ws + WBh_off);
  _Float16* WBl = (_Float16*)(ws + WBl_off);
  double* PART = (double*)(ws + PART_off);
  float* CAB = ws + CAB_off;
  float* CSC = ws + CSC_off;
  float* CCL = ws + CCL_off;
  int* GAI = (int*)(ws + GAI_off);
  unsigned* H1 = (unsigned*)(ws + H1_off);
  unsigned* H2 = (unsigned*)(ws + H2_off);
  unsigned* CNT = (unsigned*)(ws + CNT_off);
  unsigned* CTL = (unsigned*)(ws + CTL_off);
  float* EQV = ws + EQV_off;
  unsigned* EQI = (unsigned*)(ws + EQI_off);
  float* LG = ws + LG_off;
  float* SF = ws + SF_off;
  float* RG = ws + RG_off;
  float* BX = ws + BX_off;
  float* CBX = ws + CBX_off;
  float* COB = ws + COB_off;
  float* SSCs = ws + SSCs_off;
  float* SARs = ws + SARs_off;
  int* SIDXs = (int*)(ws + SIDX_off);
  float4* SOXs = (float4*)(ws + SOXs_off);
  unsigned long long* MATp = (unsigned long long*)(ws + MAT_off);

  hipMemsetAsync(CSC, 0, (CTL_off + 32 - CSC_off) * sizeof(float), stream);

  dim3 blk(256);
  for (int ll = 0; ll < 4; ++ll)
    hipLaunchKernelGGL(k_rep, dim3(2304), blk, 0, stream,
                       cls_w + (size_t)ll * 589824, (const float*)nullptr,
                       WTh + (size_t)ll * 589824, WTl + (size_t)ll * 589824, 256, 256);
  hipLaunchKernelGGL(k_rep, dim3(1152), blk, 0, stream, score_w, ctr_w, WSh, WSl, 80, 128);
  hipLaunchKernelGGL(k_rep, dim3(576), blk, 0, stream, bbox_w, (const float*)nullptr,
                     WBh, WBl, 4, 64);

  hipLaunchKernelGGL(k_tf, dim3(319, 2), blk, 0, stream, fp, B);

  dim3 gT(TT, 4, 2), gH(TT, 1, 2), gB1(TT, 1, 2);
  // ---- cls tower (oc-split: y=4, NT=1)
  hipLaunchKernelGGL((k_cmf<false, true, false, 1>), gT, blk, 0, stream,
                     B, WTh, WTl, cls_b, (const float*)nullptr, CAB, A, 256, 256, 256, PART);
  hipLaunchKernelGGL(k_coef, dim3(320), blk, 0, stream, PART, cls_gs, cls_gb, CAB);
  hipLaunchKernelGGL((k_cmf<true, true, false, 1>), gT, blk, 0, stream,
                     A, WTh + 589824, WTl + 589824, cls_b + 256, (const float*)nullptr, CAB, B, 256, 256, 256, PART);
  hipLaunchKernelGGL(k_coef, dim3(320), blk, 0, stream, PART, cls_gs + 256, cls_gb + 256, CAB);
  hipLaunchKernelGGL((k_cmf<true, true, false, 1>), gT, blk, 0, stream,
                     B, WTh + 2 * 589824, WTl + 2 * 589824, cls_b + 512, (const float*)nullptr, CAB, A, 256, 256, 256, PART);
  hipLaunchKernelGGL(k_coef, dim3(320), blk, 0, stream, PART, cls_gs + 512, cls_gb + 512, CAB);
  hipLaunchKernelGGL((k_cmf<true, true, false, 1>), gT, blk, 0, stream,
                     A, WTh + 3 * 589824, WTl + 3 * 589824, cls_b + 768, (const float*)nullptr, CAB, B, 256, 256, 256, PART);
  hipLaunchKernelGGL(k_coef, dim3(320), blk, 0, stream, PART, cls_gs + 768, cls_gb + 768, CAB);

  // ---- score+ctr head: B -> LG (in A); by=0, NT=2 covers 128-pad
  hipLaunchKernelGGL((k_cmf<true, false, true, 2>), gH, blk, 0, stream,
                     B, WSh, WSl, score_b, ctr_b, CAB, LG, 96, 81, 128, (double*)nullptr);

  // ---- scores + exact top-1000
  hipLaunchKernelGGL(k_dscore, dim3(12667), blk, 0, stream, LG, SF);
  hipLaunchKernelGGL(k_hist1, dim3(128, 10), blk, 0, stream, SF, H1);
  hipLaunchKernelGGL(k_resolve1, dim3(10), blk, 0, stream, H1, CTL);
  hipLaunchKernelGGL(k_hist2, dim3(128, 10), blk, 0, stream, SF, CTL, H2);
  hipLaunchKernelGGL(k_resolve2, dim3(10), blk, 0, stream, H2, CTL, CTL);
  hipLaunchKernelGGL(k_compact, dim3(128, 10), blk, 0, stream, SF, CTL, CNT, EQV, EQI, CSC, CCL, GAI);
  hipLaunchKernelGGL(k_eq, dim3(10), blk, 0, stream, EQV, EQI, CNT, CSC, CCL, GAI);

  // ---- box tower weights + re-transpose feats
  for (int ll = 0; ll < 4; ++ll)
    hipLaunchKernelGGL(k_rep, dim3(2304), blk, 0, stream,
                       box_w + (size_t)ll * 589824, (const float*)nullptr,
                       WTh + (size_t)ll * 589824, WTl + (size_t)ll * 589824, 256, 256);
  hipLaunchKernelGGL(k_tf, dim3(319, 2), blk, 0, stream, fp, B);

  // ---- box tower
  hipLaunchKernelGGL((k_cmf<false, true, false, 1>), gT, blk, 0, stream,
                     B, WTh, WTl, box_b, (const float*)nullptr, CAB, A, 256, 256, 256, PART);
  hipLaunchKernelGGL(k_coef, dim3(320), blk, 0, stream, PART, box_gs, box_gb, CAB);
  hipLaunchKernelGGL((k_cmf<true, true, false, 1>), gT, blk, 0, stream,
                     A, WTh + 589824, WTl + 589824, box_b + 256, (const float*)nullptr, CAB, B, 256, 256, 256, PART);
  hipLaunchKernelGGL(k_coef, dim3(320), blk, 0, stream, PART, box_gs + 256, box_gb + 256, CAB);
  hipLaunchKernelGGL((k_cmf<true, true, false, 1>), gT, blk, 0, stream,
                     B, WTh + 2 * 589824, WTl + 2 * 589824, box_b + 512, (const float*)nullptr, CAB, A, 256, 256, 256, PART);
  hipLaunchKernelGGL(k_coef, dim3(320), blk, 0, stream, PART, box_gs + 512, box_gb + 512, CAB);
  hipLaunchKernelGGL((k_cmf<true, true, false, 1>), gT, blk, 0, stream,
                     A, WTh + 3 * 589824, WTl + 3 * 589824, box_b + 768, (const float*)nullptr, CAB, B, 256, 256, 256, PART);
  hipLaunchKernelGGL(k_coef, dim3(320), blk, 0, stream, PART, box_gs + 768, box_gb + 768, CAB);

  // ---- bbox head: B -> RG (in A)
  hipLaunchKernelGGL((k_cmf<true, false, false, 1>), gB1, blk, 0, stream,
                     B, WBh, WBl, bbox_b, (const float*)nullptr, CAB, RG, 8, 4, 64, (double*)nullptr);

  // ---- boxes, gather, bitmatrix NMS
  hipLaunchKernelGGL(k_dbox, dim3(159), blk, 0, stream, RG, scales, BX);
  hipLaunchKernelGGL(k_gather, dim3(40), blk, 0, stream, GAI, CCL, BX, CBX, COB);
  hipLaunchKernelGGL(k_rank, dim3(40), blk, 0, stream, CSC, COB, SSCs, SARs, SIDXs, SOXs);
  hipLaunchKernelGGL(k_bmat, dim3(1250, 2), blk, 0, stream, SOXs, SARs, MATp);
  hipLaunchKernelGGL(k_walk, dim3(2), dim3(64), 0, stream, SSCs, SIDXs, MATp, CBX, CCL,
                     (float*)d_out);
}

// Round 14
// 1689.452 us; speedup vs baseline: 1.0759x; 1.0759x over previous
//
#include <hip/hip_runtime.h>
#include <math.h>

// FCOS RPN head, R14: revert to R11 (measured best, 1690us). R12 (B-load
// prefetch) and R13 (by=4/NT=1 split) both regressed; the 2-barrier K-loop
// template plateaus at ~42% MfmaUtil (documented m97-family ceiling; barrier
// drain is structural). by=2/NT=2 oc-split towers; split-f16 MFMA conv;
// bitmatrix NMS; exact top-k. All stages bit-identical selections.

#define KCLS 80
#define TOPKK 1000
#define NCAND 5000
#define MAXDET 100
#define TOTHW 20267
#define TT 345

constexpr int cHa[5]  = {100, 50, 25, 13, 7};
constexpr int cWa[5]  = {152, 76, 38, 19, 10};
constexpr int cHWa[5] = {15200, 3800, 950, 247, 70};
constexpr int cPa[5]  = {0, 15200, 19000, 19950, 20197};
constexpr int cTXa[5] = {19, 10, 5, 3, 2};
constexpr int cPTa[5] = {0, 247, 317, 337, 343};
constexpr int cTa[5]  = {247, 70, 20, 6, 2};
constexpr float cSa[5] = {8.f, 16.f, 32.f, 64.f, 128.f};
constexpr int cPCh[5] = {0, 238, 298, 313, 317};

typedef _Float16 h8 __attribute__((ext_vector_type(8)));
typedef float f4 __attribute__((ext_vector_type(4)));

struct FeatPtrs { const float* p[5]; };

__device__ __forceinline__ int lvl_of_tile(int bx) {
  return (bx < 247) ? 0 : (bx < 317) ? 1 : (bx < 337) ? 2 : (bx < 343) ? 3 : 4;
}
__device__ __forceinline__ int lvl_of_pix(int gi) {
  return (gi < 15200) ? 0 : (gi < 19000) ? 1 : (gi < 19950) ? 2 : (gi < 20197) ? 3 : 4;
}

// ---------------- feats transpose: [c][H][W] -> FT[n][gi][256] --------------
__global__ __launch_bounds__(256) void k_tf(FeatPtrs fp, float* __restrict__ FT) {
  int b = blockIdx.x, n = blockIdx.y;
  int l = (b < 238) ? 0 : (b < 298) ? 1 : (b < 313) ? 2 : (b < 317) ? 3 : 4;
  int ch = b - cPCh[l];
  int HW = cHWa[l];
  int px0 = ch * 64;
  const float* src = fp.p[l] + (size_t)n * 256 * HW;
  __shared__ float tile[64][65];
  int tid = threadIdx.x;
  int a0 = tid & 63, a1 = tid >> 6;
  for (int icc = 0; icc < 256; icc += 64) {
    __syncthreads();
#pragma unroll
    for (int j = 0; j < 16; ++j) {
      int ic = icc + a1 * 16 + j;
      int px = px0 + a0;
      tile[a0][a1 * 16 + j] = (px < HW) ? src[(size_t)ic * HW + px] : 0.f;
    }
    __syncthreads();
#pragma unroll
    for (int j = 0; j < 16; ++j) {
      int pxl = a1 * 16 + j;
      int px = px0 + pxl;
      if (px < HW)
        FT[((size_t)(n * TOTHW + cPa[l] + px)) * 256 + icc + a0] = tile[pxl][a0];
    }
  }
}

// ---------------- weight repack to MFMA B-fragment order, f16 split ----------
__global__ void k_rep(const float* __restrict__ w, const float* __restrict__ w2,
                      _Float16* __restrict__ Wh, _Float16* __restrict__ Wl,
                      int OC, int OCpad) {
  int i = blockIdx.x * 256 + threadIdx.x;
  int tot = 2304 * OCpad;
  if (i >= tot) return;
  int j = i & 7, kh = (i >> 3) & 3, c = (i >> 5) & 15;
  int rest = i >> 9;
  int G = OCpad >> 4;
  int g = rest % G, ti = rest / G;
  int ics = ti & 7, t = ti >> 3;
  int oc = g * 16 + c, ic = ics * 32 + kh * 8 + j;
  float v = 0.f;
  if (oc < OC) v = w[((size_t)oc * 256 + ic) * 9 + t];
  else if (w2 != nullptr && oc == OC) v = w2[(size_t)ic * 9 + t];
  float sv = v * 2048.f;
  _Float16 h = (_Float16)sv;
  Wh[i] = h;
  Wl[i] = (_Float16)(sv - (float)h);
}

// ---------------- MFMA conv3x3 pad=1 Cin=256, all levels batched -------------
template<bool AFFINE, bool GN_PART, bool HEAD, int NT>
__global__ __launch_bounds__(256) void k_cmf(
    const float* __restrict__ actIn,
    const _Float16* __restrict__ Wh, const _Float16* __restrict__ Wl,
    const float* __restrict__ bias1, const float* __restrict__ bias2,
    const float* __restrict__ cab, float* __restrict__ out,
    int outCH, int OC, int OCpad, double* __restrict__ part) {
  const int bx = blockIdx.x;
  const int by = blockIdx.y;
  const int lvl = lvl_of_tile(bx);
  const int tile = bx - cPTa[lvl];
  const int H = cHa[lvl], W = cWa[lvl];
  const int tx0 = (tile % cTXa[lvl]) * 8, ty0 = (tile / cTXa[lvl]) * 8;
  const int n = blockIdx.z;
  const int t = threadIdx.x, wv = t >> 6, lane = t & 63;
  const int kh = lane >> 4, c = lane & 15;
  const int Gt = OCpad >> 4;
  const int wsel = by * 128 + wv * (NT * 16);

  __shared__ _Float16 sH[6400];
  __shared__ _Float16 sL[6400];

  const float* cabL = cab + (size_t)(lvl * 2 + n) * 512;

  const float* sp[4];
  int shp[4], sgp[4];
  bool sinb[4], shas[4];
#pragma unroll
  for (int s = 0; s < 4; ++s) {
    int e = t + 256 * s;
    bool has = e < 800;
    int grp = e & 7, hp = e >> 3;
    if (hp > 99) hp = 99;
    int yy = hp / 10, xx = hp % 10;
    int gy = ty0 + yy - 1, gx = tx0 + xx - 1;
    bool inb = has && ((unsigned)gy < (unsigned)H) && ((unsigned)gx < (unsigned)W);
    int gpx = inb ? (cPa[lvl] + gy * W + gx) : 0;
    sp[s] = actIn + ((size_t)(n * TOTHW + gpx)) * 256 + grp * 8;
    shp[s] = hp; sgp[s] = grp; sinb[s] = inb; shas[s] = has;
  }

  f4 acc[4][NT];
#pragma unroll
  for (int m = 0; m < 4; ++m)
#pragma unroll
    for (int nt = 0; nt < NT; ++nt) acc[m][nt] = (f4)(0.f);

  float4 fv[4][2];
#pragma unroll
  for (int s = 0; s < 4; ++s) {
    if (sinb[s]) {
      fv[s][0] = *(const float4*)(sp[s]);
      fv[s][1] = *(const float4*)(sp[s] + 4);
    } else {
      fv[s][0] = make_float4(0.f, 0.f, 0.f, 0.f);
      fv[s][1] = make_float4(0.f, 0.f, 0.f, 0.f);
    }
  }

  const int lB = (c * 4 + kh) * 8;

#pragma unroll 1
  for (int icc = 0; icc < 256; icc += 64) {
    __syncthreads();
#pragma unroll
    for (int s = 0; s < 4; ++s) {
      if (shas[s]) {
        float vv[8];
        vv[0] = fv[s][0].x; vv[1] = fv[s][0].y; vv[2] = fv[s][0].z; vv[3] = fv[s][0].w;
        vv[4] = fv[s][1].x; vv[5] = fv[s][1].y; vv[6] = fv[s][1].z; vv[7] = fv[s][1].w;
        if (AFFINE && sinb[s]) {
#pragma unroll
          for (int j = 0; j < 8; ++j) {
            int ch = icc + sgp[s] * 8 + j;
            vv[j] = fmaxf(0.f, fmaf(vv[j], cabL[2 * ch], cabL[2 * ch + 1]));
          }
        }
        h8 hv, lv2;
#pragma unroll
        for (int j = 0; j < 8; ++j) {
          float sv = vv[j] * 32.f;
          _Float16 hh = (_Float16)sv;
          hv[j] = hh;
          lv2[j] = (_Float16)(sv - (float)hh);
        }
        int boff = ((shp[s] << 7) + (sgp[s] << 4)) ^ ((shp[s] & 7) << 4);
        *(h8*)((char*)sH + boff) = hv;
        *(h8*)((char*)sL + boff) = lv2;
      }
    }
    if (icc < 192) {
#pragma unroll
      for (int s = 0; s < 4; ++s) {
        if (sinb[s]) {
          fv[s][0] = *(const float4*)(sp[s] + icc + 64);
          fv[s][1] = *(const float4*)(sp[s] + icc + 68);
        }
      }
    }
    __syncthreads();

#pragma unroll 1
    for (int dy = 0; dy < 3; ++dy) {
#pragma unroll 1
      for (int dx = 0; dx < 3; ++dx) {
        const int t9 = dy * 3 + dx;
#pragma unroll
        for (int ics = 0; ics < 2; ++ics) {
          const int ICS = (icc >> 5) + ics;
          size_t wb = ((size_t)(t9 * 8 + ICS) * Gt + by * 8 + wv * NT) * 512 + lB;
          h8 bh[NT], bl[NT];
#pragma unroll
          for (int nt = 0; nt < NT; ++nt) {
            bh[nt] = *(const h8*)(Wh + wb + nt * 512);
            bl[nt] = *(const h8*)(Wl + wb + nt * 512);
          }
#pragma unroll
          for (int m = 0; m < 4; ++m) {
            int pxA = m * 16 + c;
            int hpA = ((pxA >> 3) + dy) * 10 + (pxA & 7) + dx;
            int boffA = ((hpA << 7) + (ics << 6) + (kh << 4)) ^ ((hpA & 7) << 4);
            h8 Ah = *(const h8*)((const char*)sH + boffA);
            h8 Al = *(const h8*)((const char*)sL + boffA);
#pragma unroll
            for (int nt = 0; nt < NT; ++nt) {
              acc[m][nt] = __builtin_amdgcn_mfma_f32_16x16x32_f16(Ah, bh[nt], acc[m][nt], 0, 0, 0);
              acc[m][nt] = __builtin_amdgcn_mfma_f32_16x16x32_f16(Ah, bl[nt], acc[m][nt], 0, 0, 0);
              acc[m][nt] = __builtin_amdgcn_mfma_f32_16x16x32_f16(Al, bh[nt], acc[m][nt], 0, 0, 0);
            }
          }
        }
      }
    }
  }

  const float inv = 1.f / 65536.f;
#pragma unroll
  for (int nt = 0; nt < NT; ++nt) {
    int oc = wsel + nt * 16 + c;
    float bb;
    if (HEAD) bb = (oc < KCLS) ? bias1[oc] : (oc == KCLS ? bias2[0] : 0.f);
    else bb = (oc < OC) ? bias1[oc] : 0.f;
    double s = 0.0, ss = 0.0;
#pragma unroll
    for (int m = 0; m < 4; ++m) {
#pragma unroll
      for (int r = 0; r < 4; ++r) {
        int px = m * 16 + kh * 4 + r;
        int oy = ty0 + (px >> 3), ox = tx0 + (px & 7);
        bool vpx = (oy < H) && (ox < W);
        float y = fmaf(acc[m][nt][r], inv, bb);
        if (vpx && oc < OC)
          out[((size_t)(n * TOTHW + cPa[lvl] + oy * W + ox)) * outCH + oc] = y;
        if (GN_PART && vpx) { double d = (double)y; s += d; ss += d * d; }
      }
    }
    if (GN_PART) {
#pragma unroll
      for (int msk = 16; msk <= 32; msk <<= 1) {
        s += __shfl_xor(s, msk, 64);
        ss += __shfl_xor(ss, msk, 64);
      }
#pragma unroll
      for (int msk = 1; msk <= 4; msk <<= 1) {
        s += __shfl_xor(s, msk, 64);
        ss += __shfl_xor(ss, msk, 64);
      }
      if (lane == 0 || lane == 8) {
        int G = by * 16 + wv * (NT * 2) + nt * 2 + (lane >> 3);
        size_t sl = (((size_t)bx * 2 + n) * 32 + G) * 2;
        part[sl] = s;
        part[sl + 1] = ss;
      }
    }
  }
}

// ---------------- GN coef from per-tile partials -----------------------------
__global__ __launch_bounds__(256) void k_coef(const double* __restrict__ part,
                                              const float* __restrict__ gs,
                                              const float* __restrict__ gb,
                                              float* __restrict__ cab) {
  int l = blockIdx.x >> 6, ng = blockIdx.x & 63, n = ng >> 5, g = ng & 31;
  int T = cTa[l];
  double s = 0.0, ss = 0.0;
  for (int tt = threadIdx.x; tt < T; tt += 256) {
    size_t sl = (((size_t)(cPTa[l] + tt) * 2 + n) * 32 + g) * 2;
    s += part[sl]; ss += part[sl + 1];
  }
  __shared__ double rs[256], rss[256];
  rs[threadIdx.x] = s; rss[threadIdx.x] = ss;
  __syncthreads();
  for (int off = 128; off > 0; off >>= 1) {
    if (threadIdx.x < off) {
      rs[threadIdx.x] += rs[threadIdx.x + off];
      rss[threadIdx.x] += rss[threadIdx.x + off];
    }
    __syncthreads();
  }
  if (threadIdx.x == 0) {
    int len = 8 * cHWa[l];
    double mu = rs[0] / len;
    double var = rss[0] / len - mu * mu;
    double rsq = 1.0 / sqrt(var + 1e-5);
    for (int cc = 0; cc < 8; ++cc) {
      int ch = g * 8 + cc;
      double A = rsq * (double)gs[ch];
      cab[((size_t)(l * 2 + n) * 256 + ch) * 2] = (float)A;
      cab[((size_t)(l * 2 + n) * 256 + ch) * 2 + 1] = (float)((double)gb[ch] - mu * A);
    }
  }
}

// ---------------- decode scores ---------------------------------------------
__global__ void k_dscore(const float* __restrict__ LG, float* __restrict__ SF) {
  size_t i = (size_t)blockIdx.x * 256 + threadIdx.x;
  size_t tot = (size_t)2 * TOTHW * 80;
  if (i >= tot) return;
  int c = (int)(i % 80);
  size_t g = i / 80;
  const float* base = LG + g * 96;
  float lg = base[c];
  float ct = base[80];
  float s1 = 1.f / (1.f + expf(-lg));
  float s2 = 1.f / (1.f + expf(-ct));
  SF[i] = sqrtf(s1 * s2);
}

// ---------------- decode boxes ----------------------------------------------
__global__ void k_dbox(const float* __restrict__ RG, const float* __restrict__ scales,
                       float* __restrict__ BX) {
  int i = blockIdx.x * 256 + threadIdx.x;
  if (i >= 2 * TOTHW) return;
  int gi = i % TOTHW;
  int l = lvl_of_pix(gi);
  int a = gi - cPa[l];
  int W = cWa[l];
  const float* rg = RG + (size_t)i * 8;
  float sc = scales[l];
  float stride = cSa[l];
  float r0 = fmaxf(0.f, sc * rg[0]);
  float r1 = fmaxf(0.f, sc * rg[1]);
  float r2 = fmaxf(0.f, sc * rg[2]);
  float r3 = fmaxf(0.f, sc * rg[3]);
  int x = a % W, yv = a / W;
  float px = (x + 0.5f) * stride, py = (yv + 0.5f) * stride;
  float* bp = BX + (size_t)i * 4;
  bp[0] = px - r0 * stride; bp[1] = py - r1 * stride;
  bp[2] = px + r2 * stride; bp[3] = py + r3 * stride;
}

// ---------------- exact top-1000 per (n,level) -------------------------------
__global__ void k_hist1(const float* __restrict__ SF, unsigned* __restrict__ hist) {
  int nl = blockIdx.y; int n = nl & 1, l = nl >> 1;
  const float* s = SF + ((size_t)n * TOTHW + cPa[l]) * 80;
  int M = cHWa[l] * 80;
  unsigned* h = hist + nl * 1024;
  __shared__ unsigned lh[1024];
  for (int i = threadIdx.x; i < 1024; i += blockDim.x) lh[i] = 0;
  __syncthreads();
  for (int i = blockIdx.x * blockDim.x + threadIdx.x; i < M; i += gridDim.x * blockDim.x) {
    unsigned key = __float_as_uint(s[i]);
    unsigned b = key >> 20; if (b > 1023u) b = 1023u;
    atomicAdd(&lh[b], 1u);
  }
  __syncthreads();
  for (int i = threadIdx.x; i < 1024; i += blockDim.x)
    if (lh[i]) atomicAdd(&h[i], lh[i]);
}

__global__ __launch_bounds__(256) void k_resolve1(const unsigned* __restrict__ hist,
                                                  unsigned* __restrict__ ctl) {
  int nl = blockIdx.x;
  const unsigned* h = hist + nl * 1024;
  int t = threadIdx.x;
  unsigned loc[4];
  unsigned chunk = 0;
#pragma unroll
  for (int j = 0; j < 4; ++j) { loc[j] = h[t * 4 + j]; chunk += loc[j]; }
  __shared__ unsigned csum[256];
  csum[t] = chunk;
  __syncthreads();
  for (int off = 1; off < 256; off <<= 1) {
    unsigned v = (t + off < 256) ? csum[t + off] : 0u;
    __syncthreads();
    csum[t] += v;
    __syncthreads();
  }
  unsigned above = csum[t] - chunk;
  unsigned sfx[5];
  sfx[4] = above;
#pragma unroll
  for (int j = 3; j >= 0; --j) sfx[j] = sfx[j + 1] + loc[j];
#pragma unroll
  for (int j = 0; j < 4; ++j) {
    if (sfx[j] >= TOPKK && sfx[j + 1] < TOPKK) {
      ctl[nl] = (unsigned)(t * 4 + j);
      ctl[10 + nl] = sfx[j + 1];
    }
  }
}

__global__ void k_hist2(const float* __restrict__ SF, const unsigned* __restrict__ ctl,
                        unsigned* __restrict__ hist2) {
  int nl = blockIdx.y; int n = nl & 1, l = nl >> 1;
  unsigned b1 = ctl[nl];
  const float* s = SF + ((size_t)n * TOTHW + cPa[l]) * 80;
  int M = cHWa[l] * 80;
  unsigned* h = hist2 + nl * 4096;
  __shared__ unsigned lh[4096];
  for (int i = threadIdx.x; i < 4096; i += blockDim.x) lh[i] = 0;
  __syncthreads();
  for (int i = blockIdx.x * blockDim.x + threadIdx.x; i < M; i += gridDim.x * blockDim.x) {
    unsigned key = __float_as_uint(s[i]);
    if ((key >> 20) == b1) atomicAdd(&lh[(key >> 8) & 0xFFFu], 1u);
  }
  __syncthreads();
  for (int i = threadIdx.x; i < 4096; i += blockDim.x)
    if (lh[i]) atomicAdd(&h[i], lh[i]);
}

__global__ __launch_bounds__(256) void k_resolve2(const unsigned* __restrict__ hist2,
                                                  const unsigned* __restrict__ ctlin,
                                                  unsigned* __restrict__ ctl) {
  int nl = blockIdx.x;
  const unsigned* h = hist2 + nl * 4096;
  unsigned b1 = ctlin[nl];
  unsigned m1 = ctlin[10 + nl];
  int t = threadIdx.x;
  unsigned loc[16];
  unsigned chunk = 0;
#pragma unroll
  for (int j = 0; j < 16; ++j) { loc[j] = h[t * 16 + j]; chunk += loc[j]; }
  __shared__ unsigned csum[256];
  csum[t] = chunk;
  __syncthreads();
  for (int off = 1; off < 256; off <<= 1) {
    unsigned v = (t + off < 256) ? csum[t + off] : 0u;
    __syncthreads();
    csum[t] += v;
    __syncthreads();
  }
  unsigned above = csum[t] - chunk;
  unsigned sfx[17];
  sfx[16] = above;
#pragma unroll
  for (int j = 15; j >= 0; --j) sfx[j] = sfx[j + 1] + loc[j];
#pragma unroll
  for (int j = 0; j < 16; ++j) {
    if (m1 + sfx[j] >= TOPKK && m1 + sfx[j + 1] < TOPKK)
      ctl[20 + nl] = (b1 << 12) | (unsigned)(t * 16 + j);
  }
}

__device__ __forceinline__ void write_cand(int n, int l, int pos, float v, int i,
                                           float* csc, float* ccl, int* gai) {
  int a = i / KCLS, c = i - a * KCLS;
  int g = n * NCAND + pos;
  csc[g] = (v > 0.05f) ? v : 0.f;
  ccl[g] = (float)c;
  gai[g] = cPa[l] + a;
}

__global__ void k_compact(const float* __restrict__ SF, const unsigned* __restrict__ ctl,
                          unsigned* __restrict__ cnt, float* __restrict__ eqV,
                          unsigned* __restrict__ eqI,
                          float* csc, float* ccl, int* gai) {
  int nl = blockIdx.y; int n = nl & 1, l = nl >> 1;
  const float* s = SF + ((size_t)n * TOTHW + cPa[l]) * 80;
  int M = cHWa[l] * 80;
  unsigned P = ctl[20 + nl];
  int loff = l * TOPKK;
  for (int i = blockIdx.x * blockDim.x + threadIdx.x; i < M; i += gridDim.x * blockDim.x) {
    float v = s[i];
    unsigned k24 = __float_as_uint(v) >> 8;
    if (k24 < P) continue;
    if (k24 > P) {
      unsigned slot = atomicAdd(&cnt[nl], 1u);
      write_cand(n, l, loff + (int)slot, v, i, csc, ccl, gai);
    } else {
      unsigned e = atomicAdd(&cnt[10 + nl], 1u);
      if (e < 2048u) { eqV[nl * 2048 + e] = v; eqI[nl * 2048 + e] = (unsigned)i; }
    }
  }
}

__global__ void k_eq(const float* __restrict__ eqV, const unsigned* __restrict__ eqI,
                     const unsigned* __restrict__ cnt,
                     float* csc, float* ccl, int* gai) {
  int nl = blockIdx.x; int n = nl & 1, l = nl >> 1;
  int above = (int)cnt[nl];
  unsigned ec = cnt[10 + nl];
  int E = ec < 2048u ? (int)ec : 2048;
  int r = TOPKK - above;
  int loff = l * TOPKK;
  for (int e = threadIdx.x; e < E; e += blockDim.x) {
    float v = eqV[nl * 2048 + e];
    unsigned idx = eqI[nl * 2048 + e];
    int rank = 0;
    for (int j = 0; j < E; ++j) {
      float vj = eqV[nl * 2048 + j];
      unsigned ij = eqI[nl * 2048 + j];
      if (vj > v || (vj == v && ij < idx)) rank++;
    }
    if (rank < r)
      write_cand(n, l, loff + above + rank, v, (int)idx, csc, ccl, gai);
  }
}

// ---------------- gather candidate boxes -------------------------------------
__global__ void k_gather(const int* __restrict__ gai, const float* __restrict__ ccl,
                         const float* __restrict__ BX,
                         float* __restrict__ cbx, float* __restrict__ cob) {
  int i = blockIdx.x * 256 + threadIdx.x;
  if (i >= 2 * NCAND) return;
  int n = i / NCAND;
  int a = gai[i];
  if (a < 0 || a >= TOTHW) a = 0;
  const float* bp = BX + ((size_t)n * TOTHW + a) * 4;
  float b0 = bp[0], b1 = bp[1], b2 = bp[2], b3 = bp[3];
  float off = ccl[i] * 1e4f;
  cbx[(size_t)i * 4 + 0] = b0; cbx[(size_t)i * 4 + 1] = b1;
  cbx[(size_t)i * 4 + 2] = b2; cbx[(size_t)i * 4 + 3] = b3;
  cob[(size_t)i * 4 + 0] = b0 + off; cob[(size_t)i * 4 + 1] = b1 + off;
  cob[(size_t)i * 4 + 2] = b2 + off; cob[(size_t)i * 4 + 3] = b3 + off;
}

// ---------------- NMS stage 1: exact rank by (score desc, idx asc) ----------
__global__ __launch_bounds__(256) void k_rank(
    const float* __restrict__ csc, const float* __restrict__ cob,
    float* __restrict__ SSC, float* __restrict__ SAR,
    int* __restrict__ SIDX, float4* __restrict__ SOX) {
  int n = blockIdx.x / 20, seg = blockIdx.x % 20;
  int i = seg * 256 + threadIdx.x;
  bool act = i < NCAND;
  float sci = act ? csc[(size_t)n * NCAND + i] : 0.f;
  int rank = 0;
  __shared__ float tj[256];
  for (int jt = 0; jt < 20; ++jt) {
    int j = jt * 256 + threadIdx.x;
    tj[threadIdx.x] = (j < NCAND) ? csc[(size_t)n * NCAND + j] : -2.f;
    __syncthreads();
    if (act) {
      for (int k = 0; k < 256; ++k) {
        int jj = jt * 256 + k;
        float v = tj[k];
        rank += (v > sci || (v == sci && jj < i)) ? 1 : 0;
      }
    }
    __syncthreads();
  }
  if (act) {
    float4 b = *(const float4*)(cob + ((size_t)n * NCAND + i) * 4);
    size_t r = (size_t)n * NCAND + rank;
    SSC[r] = sci;
    SAR[r] = fmaxf(b.z - b.x, 0.f) * fmaxf(b.w - b.y, 0.f);
    SIDX[r] = i;
    SOX[r] = b;
  }
}

// ---------------- NMS stage 2: suppression bit-matrix (sorted order) ---------
__global__ __launch_bounds__(256) void k_bmat(
    const float4* __restrict__ SOX, const float* __restrict__ SAR,
    unsigned long long* __restrict__ mat) {
  int n = blockIdx.y;
  int i = blockIdx.x * 4 + (threadIdx.x >> 6);
  int lane = threadIdx.x & 63;
  size_t base = (size_t)n * NCAND;
  float4 bi = SOX[base + i];
  float ai = SAR[base + i];
  unsigned long long* row = mat + ((size_t)n * NCAND + i) * 80;
  for (int c = i >> 6; c < 79; ++c) {
    int j = c * 64 + lane;
    bool bit = false;
    if (j < NCAND) {
      float4 bj = SOX[base + j];
      float iw = fmaxf(fminf(bi.z, bj.z) - fmaxf(bi.x, bj.x), 0.f);
      float ih = fmaxf(fminf(bi.w, bj.w) - fmaxf(bi.y, bj.y), 0.f);
      float inter = iw * ih;
      float iou = inter / fmaxf(ai + SAR[base + j] - inter, 1e-6f);
      bit = (iou > 0.6f) || (j == i);
    }
    unsigned long long m = __ballot(bit);
    if (lane == 0) row[c] = m;
  }
}

// ---------------- NMS stage 3: 1-wave greedy walk ----------------------------
__global__ __launch_bounds__(64) void k_walk(
    const float* __restrict__ SSC, const int* __restrict__ SIDX,
    const unsigned long long* __restrict__ mat,
    const float* __restrict__ cbox, const float* __restrict__ ccls,
    float* __restrict__ out) {
  int n = blockIdx.x;
  int l = threadIdx.x;
  __shared__ float sS[NCAND];
  __shared__ int pk[MAXDET];
  __shared__ float pv[MAXDET];
  for (int j = l; j < NCAND; j += 64) sS[j] = SSC[(size_t)n * NCAND + j];
  unsigned long long a0 = ~0ull;
  unsigned long long a1 = (l < 14) ? ~0ull : (l == 14 ? 0xFFull : 0ull);
  __syncthreads();
  for (int it = 0; it < MAXDET; ++it) {
    int j0 = a0 ? (l * 64 + __ffsll((long long)a0) - 1) : (1 << 30);
    int j1 = a1 ? ((64 + l) * 64 + __ffsll((long long)a1) - 1) : (1 << 30);
    int loc = j0 < j1 ? j0 : j1;
#pragma unroll
    for (int off = 1; off < 64; off <<= 1) {
      int o = __shfl_xor(loc, off);
      loc = o < loc ? o : loc;
    }
    float bv = (loc < NCAND) ? sS[loc] : 0.f;
    if (bv > 0.f) {
      const unsigned long long* row = mat + ((size_t)n * NCAND + loc) * 80;
      a0 &= ~row[l];
      if (l < 15) a1 &= ~row[64 + l];
      if (l == 0) { pk[it] = loc; pv[it] = bv; }
    } else {
      if (l == 0) { pk[it] = -1; pv[it] = 0.f; }
    }
  }
  __syncthreads();
  for (int it = l; it < MAXDET; it += 64) {
    float* o = out + ((size_t)n * MAXDET + it) * 6;
    int p = pk[it];
    if (p >= 0) {
      int orig = SIDX[(size_t)n * NCAND + p];
      size_t g = (size_t)n * NCAND + orig;
      const float* bb = cbox + g * 4;
      o[0] = bb[0]; o[1] = bb[1]; o[2] = bb[2]; o[3] = bb[3];
      o[4] = pv[it]; o[5] = ccls[g];
    } else {
      o[0] = o[1] = o[2] = o[3] = o[4] = o[5] = 0.f;
    }
  }
}

// ---------------- host orchestration -----------------------------------------
extern "C" void kernel_launch(void* const* d_in, const int* in_sizes, int n_in,
                              void* d_out, int out_size, void* d_ws, size_t ws_size,
                              hipStream_t stream) {
  FeatPtrs fp;
  for (int i = 0; i < 5; ++i) fp.p[i] = (const float*)d_in[i];
  const float* cls_w = (const float*)d_in[5];
  const float* cls_b = (const float*)d_in[6];
  const float* cls_gs = (const float*)d_in[7];
  const float* cls_gb = (const float*)d_in[8];
  const float* box_w = (const float*)d_in[9];
  const float* box_b = (const float*)d_in[10];
  const float* box_gs = (const float*)d_in[11];
  const float* box_gb = (const float*)d_in[12];
  const float* score_w = (const float*)d_in[13];
  const float* score_b = (const float*)d_in[14];
  const float* bbox_w = (const float*)d_in[15];
  const float* bbox_b = (const float*)d_in[16];
  const float* ctr_w = (const float*)d_in[17];
  const float* ctr_b = (const float*)d_in[18];
  const float* scales = (const float*)d_in[19];

  float* ws = (float*)d_ws;
  const size_t A_off    = 0;
  const size_t B_off    = 10376704;
  const size_t WTh_off  = 20753408;
  const size_t WTl_off  = 21933056;
  const size_t WSh_off  = 23112704;
  const size_t WSl_off  = 23260160;
  const size_t WBh_off  = 23407616;
  const size_t WBl_off  = 23481344;
  const size_t PART_off = 23555072;
  const size_t CAB_off  = 23731712;
  const size_t CSC_off  = 23736832;
  const size_t CCL_off  = 23746832;
  const size_t GAI_off  = 23756832;
  const size_t H1_off   = 23766832;
  const size_t H2_off   = 23777072;
  const size_t CNT_off  = 23818032;
  const size_t CTL_off  = 23818064;
  const size_t EQV_off  = 23818096;
  const size_t EQI_off  = 23838576;
  const size_t LG_off   = A_off + 0;
  const size_t SF_off   = A_off + 4000000;
  const size_t RG_off   = A_off + 7300000;
  const size_t BX_off   = A_off + 7700000;
  const size_t CBX_off  = A_off + 7900000;
  const size_t COB_off  = A_off + 7950000;
  const size_t SSCs_off = A_off + 8000000;
  const size_t SARs_off = A_off + 8010000;
  const size_t SIDX_off = A_off + 8020000;
  const size_t SOXs_off = A_off + 8030000;
  const size_t MAT_off  = A_off + 8100000;

  float* A = ws + A_off;
  float* B = ws + B_off;
  _Float16* WTh = (_Float16*)(ws + WTh_off);
  _Float16* WTl = (_Float16*)(ws + WTl_off);
  _Float16* WSh = (_Float16*)(ws + WSh_off);
  _Float16* WSl = (_Float16*)(ws + WSl_off);
  _Float16* WBh = (_Float16*)(ws + WBh_off);
  _Float16* WBl = (_Float16*)(ws + WBl_off);
  double* PART = (double*)(ws + PART_off);
  float* CAB = ws + CAB_off;
  float* CSC = ws + CSC_off;
  float* CCL = ws + CCL_off;
  int* GAI = (int*)(ws + GAI_off);
  unsigned* H1 = (unsigned*)(ws + H1_off);
  unsigned* H2 = (unsigned*)(ws + H2_off);
  unsigned* CNT = (unsigned*)(ws + CNT_off);
  unsigned* CTL = (unsigned*)(ws + CTL_off);
  float* EQV = ws + EQV_off;
  unsigned* EQI = (unsigned*)(ws + EQI_off);
  float* LG = ws + LG_off;
  float* SF = ws + SF_off;
  float* RG = ws + RG_off;
  float* BX = ws + BX_off;
  float* CBX = ws + CBX_off;
  float* COB = ws + COB_off;
  float* SSCs = ws + SSCs_off;
  float* SARs = ws + SARs_off;
  int* SIDXs = (int*)(ws + SIDX_off);
  float4* SOXs = (float4*)(ws + SOXs_off);
  unsigned long long* MATp = (unsigned long long*)(ws + MAT_off);

  hipMemsetAsync(CSC, 0, (CTL_off + 32 - CSC_off) * sizeof(float), stream);

  dim3 blk(256);
  for (int ll = 0; ll < 4; ++ll)
    hipLaunchKernelGGL(k_rep, dim3(2304), blk, 0, stream,
                       cls_w + (size_t)ll * 589824, (const float*)nullptr,
                       WTh + (size_t)ll * 589824, WTl + (size_t)ll * 589824, 256, 256);
  hipLaunchKernelGGL(k_rep, dim3(1152), blk, 0, stream, score_w, ctr_w, WSh, WSl, 80, 128);
  hipLaunchKernelGGL(k_rep, dim3(576), blk, 0, stream, bbox_w, (const float*)nullptr,
                     WBh, WBl, 4, 64);

  hipLaunchKernelGGL(k_tf, dim3(319, 2), blk, 0, stream, fp, B);

  dim3 gT(TT, 2, 2), gH(TT, 1, 2), gB1(TT, 1, 2);
  // ---- cls tower (oc-split: y=2, NT=2)
  hipLaunchKernelGGL((k_cmf<false, true, false, 2>), gT, blk, 0, stream,
                     B, WTh, WTl, cls_b, (const float*)nullptr, CAB, A, 256, 256, 256, PART);
  hipLaunchKernelGGL(k_coef, dim3(320), blk, 0, stream, PART, cls_gs, cls_gb, CAB);
  hipLaunchKernelGGL((k_cmf<true, true, false, 2>), gT, blk, 0, stream,
                     A, WTh + 589824, WTl + 589824, cls_b + 256, (const float*)nullptr, CAB, B, 256, 256, 256, PART);
  hipLaunchKernelGGL(k_coef, dim3(320), blk, 0, stream, PART, cls_gs + 256, cls_gb + 256, CAB);
  hipLaunchKernelGGL((k_cmf<true, true, false, 2>), gT, blk, 0, stream,
                     B, WTh + 2 * 589824, WTl + 2 * 589824, cls_b + 512, (const float*)nullptr, CAB, A, 256, 256, 256, PART);
  hipLaunchKernelGGL(k_coef, dim3(320), blk, 0, stream, PART, cls_gs + 512, cls_gb + 512, CAB);
  hipLaunchKernelGGL((k_cmf<true, true, false, 2>), gT, blk, 0, stream,
                     A, WTh + 3 * 589824, WTl + 3 * 589824, cls_b + 768, (const float*)nullptr, CAB, B, 256, 256, 256, PART);
  hipLaunchKernelGGL(k_coef, dim3(320), blk, 0, stream, PART, cls_gs + 768, cls_gb + 768, CAB);

  // ---- score+ctr head: B -> LG (in A)
  hipLaunchKernelGGL((k_cmf<true, false, true, 2>), gH, blk, 0, stream,
                     B, WSh, WSl, score_b, ctr_b, CAB, LG, 96, 81, 128, (double*)nullptr);

  // ---- scores + exact top-1000
  hipLaunchKernelGGL(k_dscore, dim3(12667), blk, 0, stream, LG, SF);
  hipLaunchKernelGGL(k_hist1, dim3(128, 10), blk, 0, stream, SF, H1);
  hipLaunchKernelGGL(k_resolve1, dim3(10), blk, 0, stream, H1, CTL);
  hipLaunchKernelGGL(k_hist2, dim3(128, 10), blk, 0, stream, SF, CTL, H2);
  hipLaunchKernelGGL(k_resolve2, dim3(10), blk, 0, stream, H2, CTL, CTL);
  hipLaunchKernelGGL(k_compact, dim3(128, 10), blk, 0, stream, SF, CTL, CNT, EQV, EQI, CSC, CCL, GAI);
  hipLaunchKernelGGL(k_eq, dim3(10), blk, 0, stream, EQV, EQI, CNT, CSC, CCL, GAI);

  // ---- box tower weights + re-transpose feats
  for (int ll = 0; ll < 4; ++ll)
    hipLaunchKernelGGL(k_rep, dim3(2304), blk, 0, stream,
                       box_w + (size_t)ll * 589824, (const float*)nullptr,
                       WTh + (size_t)ll * 589824, WTl + (size_t)ll * 589824, 256, 256);
  hipLaunchKernelGGL(k_tf, dim3(319, 2), blk, 0, stream, fp, B);

  // ---- box tower
  hipLaunchKernelGGL((k_cmf<false, true, false, 2>), gT, blk, 0, stream,
                     B, WTh, WTl, box_b, (const float*)nullptr, CAB, A, 256, 256, 256, PART);
  hipLaunchKernelGGL(k_coef, dim3(320), blk, 0, stream, PART, box_gs, box_gb, CAB);
  hipLaunchKernelGGL((k_cmf<true, true, false, 2>), gT, blk, 0, stream,
                     A, WTh + 589824, WTl + 589824, box_b + 256, (const float*)nullptr, CAB, B, 256, 256, 256, PART);
  hipLaunchKernelGGL(k_coef, dim3(320), blk, 0, stream, PART, box_gs + 256, box_gb + 256, CAB);
  hipLaunchKernelGGL((k_cmf<true, true, false, 2>), gT, blk, 0, stream,
                     B, WTh + 2 * 589824, WTl + 2 * 589824, box_b + 512, (const float*)nullptr, CAB, A, 256, 256, 256, PART);
  hipLaunchKernelGGL(k_coef, dim3(320), blk, 0, stream, PART, box_gs + 512, box_gb + 512, CAB);
  hipLaunchKernelGGL((k_cmf<true, true, false, 2>), gT, blk, 0, stream,
                     A, WTh + 3 * 589824, WTl + 3 * 589824, box_b + 768, (const float*)nullptr, CAB, B, 256, 256, 256, PART);
  hipLaunchKernelGGL(k_coef, dim3(320), blk, 0, stream, PART, box_gs + 768, box_gb + 768, CAB);

  // ---- bbox head: B -> RG (in A)
  hipLaunchKernelGGL((k_cmf<true, false, false, 1>), gB1, blk, 0, stream,
                     B, WBh, WBl, bbox_b, (const float*)nullptr, CAB, RG, 8, 4, 64, (double*)nullptr);

  // ---- boxes, gather, bitmatrix NMS
  hipLaunchKernelGGL(k_dbox, dim3(159), blk, 0, stream, RG, scales, BX);
  hipLaunchKernelGGL(k_gather, dim3(40), blk, 0, stream, GAI, CCL, BX, CBX, COB);
  hipLaunchKernelGGL(k_rank, dim3(40), blk, 0, stream, CSC, COB, SSCs, SARs, SIDXs, SOXs);
  hipLaunchKernelGGL(k_bmat, dim3(1250, 2), blk, 0, stream, SOXs, SARs, MATp);
  hipLaunchKernelGGL(k_walk, dim3(2), dim3(64), 0, stream, SSCs, SIDXs, MATp, CBX, CCL,
                     (float*)d_out);
}